// Round 4
// baseline (964.270 us; speedup 1.0000x reference)
//
#include <hip/hip_runtime.h>

// NNUE fused forward. 512-thread block = TWO batch elements; each half-block
// (tb = t&255) executes the R1-passing 256-thread kernel VERBATIM (bit-exact
// FP path — the harness compares bf16-rounded with a sub-ulp threshold, so
// any FP restructuring flips outputs; R2/R3 proved this). Only addressing
// changed: shared arrays gain a [2] half-block dim, b = 2*blockIdx + h.
// __launch_bounds__(512,4) caps VGPR at 128 so 2 blocks (16 waves) fit per CU
// (R1 measured ~3.8 waves/CU, latency-bound at 31% HBM).

#define DTOT 3080          // L1 + PSQT floats per ft row

constexpr float kScale = 127.0f / 128.0f;

__device__ __forceinline__ float clip01(float x) { return fminf(fmaxf(x, 0.0f), 1.0f); }

__device__ __forceinline__ void fma4(float4& a, float s, const float4 v) {
    a.x += s * v.x; a.y += s * v.y; a.z += s * v.z; a.w += s * v.w;
}

__device__ __forceinline__ float4 mix_clip(float u, float th, const float4 w, const float4 b) {
    float4 r;
    r.x = clip01(u * w.x + th * b.x);
    r.y = clip01(u * w.y + th * b.y);
    r.z = clip01(u * w.z + th * b.z);
    r.w = clip01(u * w.w + th * b.w);
    return r;
}

__device__ __forceinline__ float4 mul_scale(const float4 a, const float4 b) {
    float4 r;
    r.x = a.x * b.x * kScale;
    r.y = a.y * b.y * kScale;
    r.z = a.z * b.z * kScale;
    r.w = a.w * b.w * kScale;
    return r;
}

__global__ __launch_bounds__(512, 4) void nnue_fused(
    const float* __restrict__ us_arr, const float* __restrict__ them_arr,
    const int* __restrict__ wi, const float* __restrict__ wv,
    const int* __restrict__ bi, const float* __restrict__ bv,
    const int* __restrict__ pidx, const int* __restrict__ lsidx,
    const float* __restrict__ ftw, const float* __restrict__ ftb,
    const float* __restrict__ l1w, const float* __restrict__ l1b,
    const float* __restrict__ l1fw, const float* __restrict__ l1fb,
    const float* __restrict__ l2w, const float* __restrict__ l2b,
    const float* __restrict__ ow, const float* __restrict__ ob,
    float* __restrict__ out)
{
    const int t  = threadIdx.x;
    const int h  = t >> 8;       // half-block id: which batch element
    const int tb = t & 255;      // R1's thread id
    const int b  = (blockIdx.x << 1) | h;

    __shared__ float4 fsh[2][768];      // f vector, 3072 floats per half
    __shared__ float psw[2][8], psb[2][8];
    __shared__ int   sidx[2][64];
    __shared__ float sval[2][64];
    __shared__ float red[2][4][16];
    __shared__ float l1c[2][16];
    __shared__ float l1x[2][30];

    if (tb < 32)      { sidx[h][tb] = wi[b * 32 + tb];      sval[h][tb] = wv[b * 32 + tb]; }
    else if (tb < 64) { sidx[h][tb] = bi[b * 32 + tb - 32]; sval[h][tb] = bv[b * 32 + tb - 32]; }
    __syncthreads();

    // Slot ownership (verbatim R1): thread tb owns float4 slots (tb, tb+384);
    // tb<128 additionally (tb+256, tb+640); tb=128,129 own psqt slots 768,769.
    const int sA = tb;
    const int sB = tb + 384;
    const int sC = (tb < 128) ? (tb + 256) : ((tb < 130) ? (768 + (tb - 128)) : -1);
    const int sD = (tb < 128) ? (tb + 640) : -1;

    const float4* fb4 = (const float4*)ftb;
    float4 aw0 = fb4[sA], aw1 = fb4[sB];
    float4 aw2 = (sC >= 0) ? fb4[sC] : float4{0.f, 0.f, 0.f, 0.f};
    float4 aw3 = (sD >= 0) ? fb4[sD] : float4{0.f, 0.f, 0.f, 0.f};
    float4 ab0 = aw0, ab1 = aw1, ab2 = aw2, ab3 = aw3;

    #pragma unroll 2
    for (int m = 0; m < 32; ++m) {
        const float4* rw = (const float4*)(ftw + (size_t)sidx[h][m]      * DTOT);
        const float4* rb = (const float4*)(ftw + (size_t)sidx[h][32 + m] * DTOT);
        const float vwm = sval[h][m], vbm = sval[h][32 + m];

        fma4(aw0, vwm, rw[sA]);
        fma4(aw1, vwm, rw[sB]);
        fma4(ab0, vbm, rb[sA]);
        fma4(ab1, vbm, rb[sB]);
        if (sC >= 0) { fma4(aw2, vwm, rw[sC]); fma4(ab2, vbm, rb[sC]); }
        if (sD >= 0) { fma4(aw3, vwm, rw[sD]); fma4(ab3, vbm, rb[sD]); }
    }

    const float usv = us_arr[b];
    const float thv = them_arr[b];

    // Phase B (verbatim R1)
    fsh[h][sA] = mul_scale(mix_clip(usv, thv, aw0, ab0), mix_clip(usv, thv, aw1, ab1));
    fsh[h][sB] = mul_scale(mix_clip(usv, thv, ab0, aw0), mix_clip(usv, thv, ab1, aw1));
    if (tb < 128) {
        fsh[h][sC] = mul_scale(mix_clip(usv, thv, aw2, ab2), mix_clip(usv, thv, aw3, ab3));
        fsh[h][sD] = mul_scale(mix_clip(usv, thv, ab2, aw2), mix_clip(usv, thv, ab3, aw3));
    } else if (tb == 128) {
        psw[h][0] = aw2.x; psw[h][1] = aw2.y; psw[h][2] = aw2.z; psw[h][3] = aw2.w;
        psb[h][0] = ab2.x; psb[h][1] = ab2.y; psb[h][2] = ab2.z; psb[h][3] = ab2.w;
    } else if (tb == 129) {
        psw[h][4] = aw2.x; psw[h][5] = aw2.y; psw[h][6] = aw2.z; psw[h][7] = aw2.w;
        psb[h][4] = ab2.x; psb[h][5] = ab2.y; psb[h][6] = ab2.z; psb[h][7] = ab2.w;
    }
    __syncthreads();

    // Phase C (verbatim R1): 16 dots of length 3072, cols {tb, tb+256, tb+512}
    const int ls = lsidx[b];
    const float* wbase = l1w + (size_t)ls * 16 * 3072;
    float acc[16];
    #pragma unroll
    for (int k = 0; k < 16; ++k) acc[k] = 0.f;

    #pragma unroll
    for (int i = 0; i < 3; ++i) {
        const int col = tb + 256 * i;
        const float4 fv = fsh[h][col];
        #pragma unroll
        for (int k = 0; k < 16; ++k) {
            const float4 w1 = ((const float4*)(wbase + (size_t)k * 3072))[col];
            const float4 w2 = ((const float4*)(l1fw + (size_t)k * 3072))[col];
            acc[k] += fv.x * (w1.x + w2.x) + fv.y * (w1.y + w2.y)
                    + fv.z * (w1.z + w2.z) + fv.w * (w1.w + w2.w);
        }
    }

    const int lane = tb & 63;
    const int wave = tb >> 6;
    #pragma unroll
    for (int k = 0; k < 16; ++k) {
        #pragma unroll
        for (int off = 32; off > 0; off >>= 1)
            acc[k] += __shfl_xor(acc[k], off, 64);
    }
    if (lane == 0) {
        #pragma unroll
        for (int k = 0; k < 16; ++k) red[h][wave][k] = acc[k];
    }
    __syncthreads();

    if (tb < 16) {
        l1c[h][tb] = red[h][0][tb] + red[h][1][tb] + red[h][2][tb] + red[h][3][tb]
                   + l1b[ls * 16 + tb] + l1fb[tb];
    }
    __syncthreads();

    if (tb < 15) {
        const float v = l1c[h][tb];
        l1x[h][tb]      = clip01(v * v * kScale);
        l1x[h][15 + tb] = clip01(v);
    }
    __syncthreads();

    float partial = 0.f;
    if (tb < 32) {
        const float* r2 = l2w + (size_t)(ls * 32 + tb) * 30;
        float s2 = l2b[ls * 32 + tb];
        #pragma unroll
        for (int i = 0; i < 30; ++i) s2 += l1x[h][i] * r2[i];
        partial = clip01(s2) * ow[ls * 32 + tb];
    }
    #pragma unroll
    for (int off = 16; off > 0; off >>= 1)
        partial += __shfl_xor(partial, off, 64);

    if (tb == 0) {
        const int pi = pidx[b];
        const float x = partial + ob[ls] + l1c[h][15]
                      + (psw[h][pi] - psb[h][pi]) * (usv - 0.5f);
        out[b] = x;
    }
}

extern "C" void kernel_launch(void* const* d_in, const int* in_sizes, int n_in,
                              void* d_out, int out_size, void* d_ws, size_t ws_size,
                              hipStream_t stream) {
    const float* us   = (const float*)d_in[0];
    const float* them = (const float*)d_in[1];
    const int*   wi   = (const int*)d_in[2];
    const float* wv   = (const float*)d_in[3];
    const int*   bi   = (const int*)d_in[4];
    const float* bv   = (const float*)d_in[5];
    const int*   pidx = (const int*)d_in[6];
    const int*   ls   = (const int*)d_in[7];
    const float* ftw  = (const float*)d_in[8];
    const float* ftb  = (const float*)d_in[9];
    const float* l1w  = (const float*)d_in[10];
    const float* l1b  = (const float*)d_in[11];
    const float* l1fw = (const float*)d_in[12];
    const float* l1fb = (const float*)d_in[13];
    const float* l2w  = (const float*)d_in[14];
    const float* l2b  = (const float*)d_in[15];
    const float* ow   = (const float*)d_in[16];
    const float* ob   = (const float*)d_in[17];
    float* out = (float*)d_out;

    const int B = in_sizes[0];          // 4096 (even)
    nnue_fused<<<B / 2, 512, 0, stream>>>(us, them, wi, wv, bi, bv, pidx, ls,
                                          ftw, ftb, l1w, l1b, l1fw, l1fb,
                                          l2w, l2b, ow, ob, out);
}

// Round 5
// 646.935 us; speedup vs baseline: 1.4905x; 1.4905x over previous
//
#include <hip/hip_runtime.h>

// NNUE fused forward. One block (512 threads, 8 waves) per batch element.
// Phase A: gather-accumulate white/black feature rows (2 x 3080 fp32),
//          3-4 float4 slots per thread; stage into LDS. (512-way parallel)
// Phase C: threads 0..255 compute 16 dots of length 3072 over cols
//          {t, t+256, t+512}; f computed on the fly from LDS accumulators.
//          NOTE: q = col mod 384 via explicit select — 384 is NOT a power of
//          two; `col & 383` was the R2/R3 correctness bug.
// Phase D: l2 (30->32) on t<32, out (32->1), psqt residual.
// __launch_bounds__(512,2): 2 blocks/CU -> 128-VGPR cap, fits without spill.

#define DTOT 3080          // L1 + PSQT floats per ft row

constexpr float kScale = 127.0f / 128.0f;

__device__ __forceinline__ float clip01(float x) { return fminf(fmaxf(x, 0.0f), 1.0f); }

__device__ __forceinline__ void fma4(float4& a, float s, const float4 v) {
    a.x += s * v.x; a.y += s * v.y; a.z += s * v.z; a.w += s * v.w;
}

__device__ __forceinline__ float4 mix_clip(float u, float th, const float4 w, const float4 b) {
    float4 r;
    r.x = clip01(u * w.x + th * b.x);
    r.y = clip01(u * w.y + th * b.y);
    r.z = clip01(u * w.z + th * b.z);
    r.w = clip01(u * w.w + th * b.w);
    return r;
}

__device__ __forceinline__ float4 mul_scale(const float4 a, const float4 b) {
    float4 r;
    r.x = a.x * b.x * kScale;
    r.y = a.y * b.y * kScale;
    r.z = a.z * b.z * kScale;
    r.w = a.w * b.w * kScale;
    return r;
}

__global__ __launch_bounds__(512, 2) void nnue_fused(
    const float* __restrict__ us_arr, const float* __restrict__ them_arr,
    const int* __restrict__ wi, const float* __restrict__ wv,
    const int* __restrict__ bi, const float* __restrict__ bv,
    const int* __restrict__ pidx, const int* __restrict__ lsidx,
    const float* __restrict__ ftw, const float* __restrict__ ftb,
    const float* __restrict__ l1w, const float* __restrict__ l1b,
    const float* __restrict__ l1fw, const float* __restrict__ l1fb,
    const float* __restrict__ l2w, const float* __restrict__ l2b,
    const float* __restrict__ ow, const float* __restrict__ ob,
    float* __restrict__ out)
{
    const int b = blockIdx.x;
    const int t = threadIdx.x;

    // LDS: accumulators for both colors. White slots 0..769, black 770..1539.
    // (slot = float4 of the 3080-float row; 768 main slots + 2 psqt slots)
    __shared__ float4 lds_acc[1540];
    __shared__ int   sidx[64];
    __shared__ float sval[64];
    __shared__ float red[4][16];
    __shared__ float l1c[16];
    __shared__ float l1x[30];

    if (t < 32)      { sidx[t] = wi[b * 32 + t];      sval[t] = wv[b * 32 + t]; }
    else if (t < 64) { sidx[t] = bi[b * 32 + t - 32]; sval[t] = bv[b * 32 + t - 32]; }
    __syncthreads();

    // Global slot index g in [0,1540): white = g, black = 770 + slot.
    // Thread t owns g0=t (white), g1=t+512 (white if t<258 else black),
    // g2=t+1024 (black). Threads 0..3 also own g3=1536+t (black 766..769).
    const int g0 = t, g1 = t + 512, g2 = t + 1024;
    const int c1 = (g1 >= 770);
    const int s0 = t;
    const int s1 = c1 ? (g1 - 770) : g1;
    const int s2 = g2 - 770;
    const bool has3 = (t < 4);
    const int s3 = 766 + t;

    const float4* fb4 = (const float4*)ftb;
    float4 a0 = fb4[s0], a1 = fb4[s1], a2 = fb4[s2];
    float4 a3 = has3 ? fb4[s3] : float4{0.f, 0.f, 0.f, 0.f};

    #pragma unroll 2
    for (int m = 0; m < 32; ++m) {
        const float4* rw = (const float4*)(ftw + (size_t)sidx[m]      * DTOT);
        const float4* rb = (const float4*)(ftw + (size_t)sidx[32 + m] * DTOT);
        const float vw = sval[m], vb = sval[32 + m];

        fma4(a0, vw, rw[s0]);
        const float4* p1 = c1 ? rb : rw;
        fma4(a1, c1 ? vb : vw, p1[s1]);
        fma4(a2, vb, rb[s2]);
        if (has3) fma4(a3, vb, rb[s3]);
    }

    lds_acc[g0] = a0;
    lds_acc[g1] = a1;
    lds_acc[g2] = a2;
    if (has3) lds_acc[1536 + t] = a3;
    __syncthreads();

    const float usv = us_arr[b];
    const float thv = them_arr[b];
    const int ls = lsidx[b];

    // Phase C: threads 0..255, cols {t, t+256, t+512}, f computed on the fly.
    const float4* w1base = (const float4*)(l1w + (size_t)ls * 16 * 3072);
    const float4* w2base = (const float4*)l1fw;

    const int lane = t & 63;
    const int wave = t >> 6;

    if (t < 256) {
        float acc[16];
        #pragma unroll
        for (int k = 0; k < 16; ++k) acc[k] = 0.f;

        #pragma unroll
        for (int i = 0; i < 3; ++i) {
            const int col = t + 256 * i;
            const int q = (col >= 384) ? (col - 384) : col;   // 384 != pow2: no mask!
            const float4 W0 = lds_acc[q],       W1 = lds_acc[q + 384];
            const float4 B0 = lds_acc[770 + q], B1 = lds_acc[770 + q + 384];
            const float4 fv = (col >= 384)
                ? mul_scale(mix_clip(usv, thv, B0, W0), mix_clip(usv, thv, B1, W1))
                : mul_scale(mix_clip(usv, thv, W0, B0), mix_clip(usv, thv, W1, B1));
            #pragma unroll
            for (int k = 0; k < 16; ++k) {
                const float4 w1 = w1base[(size_t)k * 768 + col];
                const float4 w2 = w2base[(size_t)k * 768 + col];
                acc[k] += fv.x * (w1.x + w2.x) + fv.y * (w1.y + w2.y)
                        + fv.z * (w1.z + w2.z) + fv.w * (w1.w + w2.w);
            }
        }

        #pragma unroll
        for (int k = 0; k < 16; ++k) {
            #pragma unroll
            for (int off = 32; off > 0; off >>= 1)
                acc[k] += __shfl_xor(acc[k], off, 64);
        }
        if (lane == 0) {
            #pragma unroll
            for (int k = 0; k < 16; ++k) red[wave][k] = acc[k];
        }
    }
    __syncthreads();

    if (t < 16) {
        l1c[t] = red[0][t] + red[1][t] + red[2][t] + red[3][t]
               + l1b[ls * 16 + t] + l1fb[t];
    }
    __syncthreads();

    if (t < 15) {
        const float v = l1c[t];
        l1x[t]      = clip01(v * v * kScale);
        l1x[15 + t] = clip01(v);
    }
    __syncthreads();

    float partial = 0.f;
    if (t < 32) {
        const float* r2 = l2w + (size_t)(ls * 32 + t) * 30;
        float s2 = l2b[ls * 32 + t];
        #pragma unroll
        for (int i = 0; i < 30; ++i) s2 += l1x[i] * r2[i];
        partial = clip01(s2) * ow[ls * 32 + t];
    }
    #pragma unroll
    for (int off = 16; off > 0; off >>= 1)
        partial += __shfl_xor(partial, off, 64);

    if (t == 0) {
        const int pi = pidx[b];
        const float* pw = (const float*)&lds_acc[768];        // white psqt (8 floats)
        const float* pb = (const float*)&lds_acc[770 + 768];  // black psqt
        out[b] = partial + ob[ls] + l1c[15]
               + (pw[pi] - pb[pi]) * (usv - 0.5f);
    }
}

extern "C" void kernel_launch(void* const* d_in, const int* in_sizes, int n_in,
                              void* d_out, int out_size, void* d_ws, size_t ws_size,
                              hipStream_t stream) {
    const float* us   = (const float*)d_in[0];
    const float* them = (const float*)d_in[1];
    const int*   wi   = (const int*)d_in[2];
    const float* wv   = (const float*)d_in[3];
    const int*   bi   = (const int*)d_in[4];
    const float* bv   = (const float*)d_in[5];
    const int*   pidx = (const int*)d_in[6];
    const int*   ls   = (const int*)d_in[7];
    const float* ftw  = (const float*)d_in[8];
    const float* ftb  = (const float*)d_in[9];
    const float* l1w  = (const float*)d_in[10];
    const float* l1b  = (const float*)d_in[11];
    const float* l1fw = (const float*)d_in[12];
    const float* l1fb = (const float*)d_in[13];
    const float* l2w  = (const float*)d_in[14];
    const float* l2b  = (const float*)d_in[15];
    const float* ow   = (const float*)d_in[16];
    const float* ob   = (const float*)d_in[17];
    float* out = (float*)d_out;

    const int B = in_sizes[0];
    nnue_fused<<<B, 512, 0, stream>>>(us, them, wi, wv, bi, bv, pidx, ls,
                                      ftw, ftb, l1w, l1b, l1fw, l1fb,
                                      l2w, l2b, ow, ob, out);
}

// Round 6
// 320.415 us; speedup vs baseline: 3.0094x; 2.0191x over previous
//
#include <hip/hip_runtime.h>
#include <hip/hip_fp16.h>

// NNUE fused forward, fp16-table edition.
// Per launch: (K1) convert ft_weight fp32->fp16 into d_ws (139 MB, fits L3);
// (K2) merge mw = l1_w + tile(l1f_w) into d_ws (1.57 MB fp32, exact add);
// (K3) fused kernel: gather-accumulate from fp16 table in 16-B units
// (2 float4-slots per unit; per-slot accumulation stays bias-first,
// m-ascending -> only fp16 rounding of w changes numerics, ~5e-5 at output),
// then the R5-passing phases B/C/D with phase C split into two k-halves
// (8 live accumulators, kills the R5 spill at the 128-VGPR cap).
// Fallback: ws too small -> R5 kernel verbatim.

#define DTOT 3080           // L1 + PSQT floats per ft row
#define TBL16_BYTES 138772480ull   // 22528*3080*2
#define MW_BYTES    1572864ull     // 8*16*3072*4

constexpr float kScale = 127.0f / 128.0f;

__device__ __forceinline__ float clip01(float x) { return fminf(fmaxf(x, 0.0f), 1.0f); }

__device__ __forceinline__ void fma4(float4& a, float s, const float4 v) {
    a.x += s * v.x; a.y += s * v.y; a.z += s * v.z; a.w += s * v.w;
}

__device__ __forceinline__ float4 mix_clip(float u, float th, const float4 w, const float4 b) {
    float4 r;
    r.x = clip01(u * w.x + th * b.x);
    r.y = clip01(u * w.y + th * b.y);
    r.z = clip01(u * w.z + th * b.z);
    r.w = clip01(u * w.w + th * b.w);
    return r;
}

__device__ __forceinline__ float4 mul_scale(const float4 a, const float4 b) {
    float4 r;
    r.x = a.x * b.x * kScale;
    r.y = a.y * b.y * kScale;
    r.z = a.z * b.z * kScale;
    r.w = a.w * b.w * kScale;
    return r;
}

// ---------- K1: fp32 -> fp16 table conversion ----------
__global__ __launch_bounds__(256) void convert_tbl(const float4* __restrict__ in,
                                                   uint2* __restrict__ out, int n4)
{
    union Pk { __half2 h2[2]; uint2 u2; };
    for (int i = blockIdx.x * 256 + threadIdx.x; i < n4; i += gridDim.x * 256) {
        const float4 v = in[i];
        Pk p;
        p.h2[0] = __floats2half2_rn(v.x, v.y);
        p.h2[1] = __floats2half2_rn(v.z, v.w);
        out[i] = p.u2;
    }
}

// ---------- K2: mw = l1_w + tile(l1f_w), float4-wise ----------
__global__ __launch_bounds__(256) void merge_l1(const float* __restrict__ l1w,
                                                const float* __restrict__ l1fw,
                                                float* __restrict__ mw)
{
    const int idx = blockIdx.x * 256 + threadIdx.x;   // 0..98303 float4s
    const float4* a = (const float4*)l1w;
    const float4* f = (const float4*)l1fw;
    float4* o = (float4*)mw;
    const int row = idx / 768;          // 0..127 = c*16+k
    const int k = row & 15;
    const int col = idx - row * 768;
    const float4 x = a[idx];
    const float4 y = f[k * 768 + col];
    float4 r;
    r.x = x.x + y.x; r.y = x.y + y.y; r.z = x.z + y.z; r.w = x.w + y.w;
    o[idx] = r;
}

// ---------- K3: fused main kernel, fp16 gather ----------
__global__ __launch_bounds__(512, 2) void nnue_fp16(
    const float* __restrict__ us_arr, const float* __restrict__ them_arr,
    const int* __restrict__ wi, const float* __restrict__ wv,
    const int* __restrict__ bi, const float* __restrict__ bv,
    const int* __restrict__ pidx, const int* __restrict__ lsidx,
    const __half* __restrict__ tbl, const float* __restrict__ ftb,
    const float* __restrict__ mw,
    const float* __restrict__ l1b, const float* __restrict__ l1fb,
    const float* __restrict__ l2w, const float* __restrict__ l2b,
    const float* __restrict__ ow, const float* __restrict__ ob,
    float* __restrict__ out)
{
    const int b = blockIdx.x;
    const int t = threadIdx.x;

    __shared__ float4 lds_acc[1540];   // white slots 0..769, black 770..1539
    __shared__ int   sidx[64];
    __shared__ float sval[64];
    __shared__ float red[4][16];
    __shared__ float l1c[16];
    __shared__ float l1x[30];

    if (t < 32)      { sidx[t] = wi[b * 32 + t];      sval[t] = wv[b * 32 + t]; }
    else if (t < 64) { sidx[t] = bi[b * 32 + t - 32]; sval[t] = bv[b * 32 + t - 32]; }
    __syncthreads();

    // 770 16-B units: unit u<385 = white pair u (slots 2u,2u+1);
    // u>=385 = black pair u-385. Thread t owns u0=t, and u1=t+512 if t<258.
    const int u0 = t;
    const bool c0 = (u0 >= 385);
    const int p0 = c0 ? (u0 - 385) : u0;
    const bool has1 = (t < 258);
    const int p1 = t + 127;            // u1 always black

    const float4* fb4 = (const float4*)ftb;
    float4 A0a = fb4[2 * p0], A0b = fb4[2 * p0 + 1];
    float4 A1a = has1 ? fb4[2 * p1] : float4{0.f, 0.f, 0.f, 0.f};
    float4 A1b = has1 ? fb4[2 * p1 + 1] : float4{0.f, 0.f, 0.f, 0.f};

    #pragma unroll 4
    for (int m = 0; m < 32; ++m) {
        const __half* rowW = tbl + (size_t)sidx[m]      * DTOT;
        const __half* rowB = tbl + (size_t)sidx[32 + m] * DTOT;
        const float vw = sval[m], vb = sval[32 + m];

        const float v0 = c0 ? vb : vw;
        const uint4 raw0 = ((const uint4*)(c0 ? rowB : rowW))[p0];
        const __half2* h0 = (const __half2*)&raw0;
        {
            const float2 q0 = __half22float2(h0[0]);
            const float2 q1 = __half22float2(h0[1]);
            const float2 q2 = __half22float2(h0[2]);
            const float2 q3 = __half22float2(h0[3]);
            A0a.x += v0 * q0.x; A0a.y += v0 * q0.y; A0a.z += v0 * q1.x; A0a.w += v0 * q1.y;
            A0b.x += v0 * q2.x; A0b.y += v0 * q2.y; A0b.z += v0 * q3.x; A0b.w += v0 * q3.y;
        }
        if (has1) {
            const uint4 raw1 = ((const uint4*)rowB)[p1];
            const __half2* h1 = (const __half2*)&raw1;
            const float2 q0 = __half22float2(h1[0]);
            const float2 q1 = __half22float2(h1[1]);
            const float2 q2 = __half22float2(h1[2]);
            const float2 q3 = __half22float2(h1[3]);
            A1a.x += vb * q0.x; A1a.y += vb * q0.y; A1a.z += vb * q1.x; A1a.w += vb * q1.y;
            A1b.x += vb * q2.x; A1b.y += vb * q2.y; A1b.z += vb * q3.x; A1b.w += vb * q3.y;
        }
    }

    {
        const int g0 = (c0 ? 770 : 0) + 2 * p0;
        lds_acc[g0] = A0a; lds_acc[g0 + 1] = A0b;
        if (has1) {
            const int g1 = 770 + 2 * p1;
            lds_acc[g1] = A1a; lds_acc[g1 + 1] = A1b;
        }
    }
    __syncthreads();

    const float usv = us_arr[b];
    const float thv = them_arr[b];
    const int ls = lsidx[b];

    // Phase C: threads 0..255, cols {t, t+256, t+512}; f computed once into
    // regs; 16 dots split into two k-halves (8 live accumulators each).
    const float4* mwbase = (const float4*)mw + (size_t)ls * 16 * 768;

    const int lane = t & 63;
    const int wave = t >> 6;

    if (t < 256) {
        float4 fvv[3];
        #pragma unroll
        for (int i = 0; i < 3; ++i) {
            const int col = t + 256 * i;
            const int q = (col >= 384) ? (col - 384) : col;   // 384 != pow2!
            const float4 W0 = lds_acc[q],       W1 = lds_acc[q + 384];
            const float4 B0 = lds_acc[770 + q], B1 = lds_acc[770 + q + 384];
            fvv[i] = (col >= 384)
                ? mul_scale(mix_clip(usv, thv, B0, W0), mix_clip(usv, thv, B1, W1))
                : mul_scale(mix_clip(usv, thv, W0, B0), mix_clip(usv, thv, W1, B1));
        }

        #pragma unroll
        for (int half = 0; half < 2; ++half) {
            float acc[8];
            #pragma unroll
            for (int k = 0; k < 8; ++k) acc[k] = 0.f;

            #pragma unroll
            for (int i = 0; i < 3; ++i) {
                const int col = t + 256 * i;
                const float4 fv = fvv[i];
                #pragma unroll
                for (int k = 0; k < 8; ++k) {
                    const float4 w1 = mwbase[(size_t)(half * 8 + k) * 768 + col];
                    acc[k] += fv.x * w1.x + fv.y * w1.y + fv.z * w1.z + fv.w * w1.w;
                }
            }

            #pragma unroll
            for (int k = 0; k < 8; ++k) {
                #pragma unroll
                for (int off = 32; off > 0; off >>= 1)
                    acc[k] += __shfl_xor(acc[k], off, 64);
            }
            if (lane == 0) {
                #pragma unroll
                for (int k = 0; k < 8; ++k) red[wave][half * 8 + k] = acc[k];
            }
        }
    }
    __syncthreads();

    if (t < 16) {
        l1c[t] = red[0][t] + red[1][t] + red[2][t] + red[3][t]
               + l1b[ls * 16 + t] + l1fb[t];
    }
    __syncthreads();

    if (t < 15) {
        const float v = l1c[t];
        l1x[t]      = clip01(v * v * kScale);
        l1x[15 + t] = clip01(v);
    }
    __syncthreads();

    float partial = 0.f;
    if (t < 32) {
        const float* r2 = l2w + (size_t)(ls * 32 + t) * 30;
        float s2 = l2b[ls * 32 + t];
        #pragma unroll
        for (int i = 0; i < 30; ++i) s2 += l1x[i] * r2[i];
        partial = clip01(s2) * ow[ls * 32 + t];
    }
    #pragma unroll
    for (int off = 16; off > 0; off >>= 1)
        partial += __shfl_xor(partial, off, 64);

    if (t == 0) {
        const int pi = pidx[b];
        const float* pw = (const float*)&lds_acc[768];        // white psqt
        const float* pb = (const float*)&lds_acc[770 + 768];  // black psqt
        out[b] = partial + ob[ls] + l1c[15]
               + (pw[pi] - pb[pi]) * (usv - 0.5f);
    }
}

// ---------- Fallback: R5 kernel verbatim (fp32 table, no workspace) ----------
__global__ __launch_bounds__(512, 2) void nnue_fused(
    const float* __restrict__ us_arr, const float* __restrict__ them_arr,
    const int* __restrict__ wi, const float* __restrict__ wv,
    const int* __restrict__ bi, const float* __restrict__ bv,
    const int* __restrict__ pidx, const int* __restrict__ lsidx,
    const float* __restrict__ ftw, const float* __restrict__ ftb,
    const float* __restrict__ l1w, const float* __restrict__ l1b,
    const float* __restrict__ l1fw, const float* __restrict__ l1fb,
    const float* __restrict__ l2w, const float* __restrict__ l2b,
    const float* __restrict__ ow, const float* __restrict__ ob,
    float* __restrict__ out)
{
    const int b = blockIdx.x;
    const int t = threadIdx.x;

    __shared__ float4 lds_acc[1540];
    __shared__ int   sidx[64];
    __shared__ float sval[64];
    __shared__ float red[4][16];
    __shared__ float l1c[16];
    __shared__ float l1x[30];

    if (t < 32)      { sidx[t] = wi[b * 32 + t];      sval[t] = wv[b * 32 + t]; }
    else if (t < 64) { sidx[t] = bi[b * 32 + t - 32]; sval[t] = bv[b * 32 + t - 32]; }
    __syncthreads();

    const int g0 = t, g1 = t + 512, g2 = t + 1024;
    const int c1 = (g1 >= 770);
    const int s0 = t;
    const int s1 = c1 ? (g1 - 770) : g1;
    const int s2 = g2 - 770;
    const bool has3 = (t < 4);
    const int s3 = 766 + t;

    const float4* fb4 = (const float4*)ftb;
    float4 a0 = fb4[s0], a1 = fb4[s1], a2 = fb4[s2];
    float4 a3 = has3 ? fb4[s3] : float4{0.f, 0.f, 0.f, 0.f};

    #pragma unroll 2
    for (int m = 0; m < 32; ++m) {
        const float4* rw = (const float4*)(ftw + (size_t)sidx[m]      * DTOT);
        const float4* rb = (const float4*)(ftw + (size_t)sidx[32 + m] * DTOT);
        const float vw = sval[m], vb = sval[32 + m];

        fma4(a0, vw, rw[s0]);
        const float4* p1 = c1 ? rb : rw;
        fma4(a1, c1 ? vb : vw, p1[s1]);
        fma4(a2, vb, rb[s2]);
        if (has3) fma4(a3, vb, rb[s3]);
    }

    lds_acc[g0] = a0;
    lds_acc[g1] = a1;
    lds_acc[g2] = a2;
    if (has3) lds_acc[1536 + t] = a3;
    __syncthreads();

    const float usv = us_arr[b];
    const float thv = them_arr[b];
    const int ls = lsidx[b];

    const float4* w1base = (const float4*)(l1w + (size_t)ls * 16 * 3072);
    const float4* w2base = (const float4*)l1fw;

    const int lane = t & 63;
    const int wave = t >> 6;

    if (t < 256) {
        float acc[16];
        #pragma unroll
        for (int k = 0; k < 16; ++k) acc[k] = 0.f;

        #pragma unroll
        for (int i = 0; i < 3; ++i) {
            const int col = t + 256 * i;
            const int q = (col >= 384) ? (col - 384) : col;
            const float4 W0 = lds_acc[q],       W1 = lds_acc[q + 384];
            const float4 B0 = lds_acc[770 + q], B1 = lds_acc[770 + q + 384];
            const float4 fv = (col >= 384)
                ? mul_scale(mix_clip(usv, thv, B0, W0), mix_clip(usv, thv, B1, W1))
                : mul_scale(mix_clip(usv, thv, W0, B0), mix_clip(usv, thv, W1, B1));
            #pragma unroll
            for (int k = 0; k < 16; ++k) {
                const float4 w1 = w1base[(size_t)k * 768 + col];
                const float4 w2 = w2base[(size_t)k * 768 + col];
                acc[k] += fv.x * (w1.x + w2.x) + fv.y * (w1.y + w2.y)
                        + fv.z * (w1.z + w2.z) + fv.w * (w1.w + w2.w);
            }
        }

        #pragma unroll
        for (int k = 0; k < 16; ++k) {
            #pragma unroll
            for (int off = 32; off > 0; off >>= 1)
                acc[k] += __shfl_xor(acc[k], off, 64);
        }
        if (lane == 0) {
            #pragma unroll
            for (int k = 0; k < 16; ++k) red[wave][k] = acc[k];
        }
    }
    __syncthreads();

    if (t < 16) {
        l1c[t] = red[0][t] + red[1][t] + red[2][t] + red[3][t]
               + l1b[ls * 16 + t] + l1fb[t];
    }
    __syncthreads();

    if (t < 15) {
        const float v = l1c[t];
        l1x[t]      = clip01(v * v * kScale);
        l1x[15 + t] = clip01(v);
    }
    __syncthreads();

    float partial = 0.f;
    if (t < 32) {
        const float* r2 = l2w + (size_t)(ls * 32 + t) * 30;
        float s2 = l2b[ls * 32 + t];
        #pragma unroll
        for (int i = 0; i < 30; ++i) s2 += l1x[i] * r2[i];
        partial = clip01(s2) * ow[ls * 32 + t];
    }
    #pragma unroll
    for (int off = 16; off > 0; off >>= 1)
        partial += __shfl_xor(partial, off, 64);

    if (t == 0) {
        const int pi = pidx[b];
        const float* pw = (const float*)&lds_acc[768];
        const float* pb = (const float*)&lds_acc[770 + 768];
        out[b] = partial + ob[ls] + l1c[15]
               + (pw[pi] - pb[pi]) * (usv - 0.5f);
    }
}

extern "C" void kernel_launch(void* const* d_in, const int* in_sizes, int n_in,
                              void* d_out, int out_size, void* d_ws, size_t ws_size,
                              hipStream_t stream) {
    const float* us   = (const float*)d_in[0];
    const float* them = (const float*)d_in[1];
    const int*   wi   = (const int*)d_in[2];
    const float* wv   = (const float*)d_in[3];
    const int*   bi   = (const int*)d_in[4];
    const float* bv   = (const float*)d_in[5];
    const int*   pidx = (const int*)d_in[6];
    const int*   ls   = (const int*)d_in[7];
    const float* ftw  = (const float*)d_in[8];
    const float* ftb  = (const float*)d_in[9];
    const float* l1w  = (const float*)d_in[10];
    const float* l1b  = (const float*)d_in[11];
    const float* l1fw = (const float*)d_in[12];
    const float* l1fb = (const float*)d_in[13];
    const float* l2w  = (const float*)d_in[14];
    const float* l2b  = (const float*)d_in[15];
    const float* ow   = (const float*)d_in[16];
    const float* ob   = (const float*)d_in[17];
    float* out = (float*)d_out;

    const int B = in_sizes[0];
    const size_t need = TBL16_BYTES + MW_BYTES;

    if (ws_size >= need) {
        __half* tbl16 = (__half*)d_ws;
        float*  mw    = (float*)((char*)d_ws + TBL16_BYTES);
        convert_tbl<<<2048, 256, 0, stream>>>((const float4*)ftw, (uint2*)d_ws, 17346560);
        merge_l1<<<384, 256, 0, stream>>>(l1w, l1fw, mw);
        nnue_fp16<<<B, 512, 0, stream>>>(us, them, wi, wv, bi, bv, pidx, ls,
                                         tbl16, ftb, mw, l1b, l1fb,
                                         l2w, l2b, ow, ob, out);
    } else {
        nnue_fused<<<B, 512, 0, stream>>>(us, them, wi, wv, bi, bv, pidx, ls,
                                          ftw, ftb, l1w, l1b, l1fw, l1fb,
                                          l2w, l2b, ow, ob, out);
    }
}